// Round 1
// baseline (159.596 us; speedup 1.0000x reference)
//
#include <hip/hip_runtime.h>
#include <math.h>

#define NPROP 2000
#define NCLS  81
#define NFG   80
#define NDET  100
#define NBLK  256

#define IMGW 800.0f
#define IMGH 800.0f
#define SCORE_THRESH 0.05f
#define NMS_THRESH 0.5f
#define MIN_SIZE 1.0f
#define BBOX_CLIP 4.135166556742356f  // log(1000/16)

// ---------------- kernel 1: row softmax over 81 classes ----------------
__global__ void softmax_kernel(const float* __restrict__ logits,
                               float* __restrict__ probs) {
    int n = blockIdx.x * blockDim.x + threadIdx.x;
    if (n >= NPROP) return;
    const float* row = logits + n * NCLS;
    float m = -1e30f;
    for (int c = 0; c < NCLS; ++c) m = fmaxf(m, row[c]);
    float sum = 0.0f;
    for (int c = 0; c < NCLS; ++c) sum += expf(row[c] - m);
    float* prow = probs + n * NCLS;
    for (int c = 0; c < NCLS; ++c) prow[c] = expf(row[c] - m) / sum;
}

// ---------------- kernel 2: one block per foreground class ----------------
__global__ __launch_bounds__(NBLK) void perclass_kernel(
        const float* __restrict__ probs,
        const float* __restrict__ reg,     // [NPROP, NCLS*4]
        const float* __restrict__ prop,    // [NPROP, 4]
        float* __restrict__ out) {
    const int c   = blockIdx.x + 1;   // foreground class 1..80
    const int tid = threadIdx.x;

    __shared__ float s_x1[NPROP], s_y1[NPROP], s_x2[NPROP], s_y2[NPROP];
    __shared__ float s_sc[NPROP];           // score if valid else -1
    __shared__ unsigned short s_vlist[NPROP];
    __shared__ unsigned short s_ord[NPROP];
    __shared__ unsigned char  s_keep[NPROP];
    __shared__ unsigned short s_keepOut[NDET], s_supOut[NDET], s_invOut[NDET];
    __shared__ int s_cnt, s_K;

    if (tid == 0) s_cnt = 0;
    __syncthreads();

    // --- decode + clip + validity, build (unordered) valid list ---
    for (int n = tid; n < NPROP; n += NBLK) {
        float sc = probs[n * NCLS + c];
        float x1 = prop[n * 4 + 0], y1 = prop[n * 4 + 1];
        float x2 = prop[n * 4 + 2], y2 = prop[n * 4 + 3];
        float w  = x2 - x1, h = y2 - y1;
        float cx = x1 + 0.5f * w, cy = y1 + 0.5f * h;
        const float* d = reg + (size_t)n * (NCLS * 4) + c * 4;
        float dx = d[0] / 10.0f;
        float dy = d[1] / 10.0f;
        float dw = fminf(d[2] / 5.0f, BBOX_CLIP);
        float dh = fminf(d[3] / 5.0f, BBOX_CLIP);
        float pcx = dx * w + cx;
        float pcy = dy * h + cy;
        float pw  = expf(dw) * w;
        float ph  = expf(dh) * h;
        float bx1 = fminf(fmaxf(pcx - 0.5f * pw, 0.0f), IMGW);
        float by1 = fminf(fmaxf(pcy - 0.5f * ph, 0.0f), IMGH);
        float bx2 = fminf(fmaxf(pcx + 0.5f * pw, 0.0f), IMGW);
        float by2 = fminf(fmaxf(pcy + 0.5f * ph, 0.0f), IMGH);
        s_x1[n] = bx1; s_y1[n] = by1; s_x2[n] = bx2; s_y2[n] = by2;
        bool valid = (sc >= SCORE_THRESH) && ((bx2 - bx1) >= MIN_SIZE)
                                          && ((by2 - by1) >= MIN_SIZE);
        s_sc[n] = valid ? sc : -1.0f;
        if (valid) {
            int p = atomicAdd(&s_cnt, 1);
            s_vlist[p] = (unsigned short)n;
        }
    }
    __syncthreads();
    const int V = s_cnt;

    // --- rank sort of valid items: (score desc, index asc) — stable total order ---
    for (int i = tid; i < V; i += NBLK) {
        int ni = s_vlist[i];
        float si = s_sc[ni];
        int r = 0;
        for (int j = 0; j < V; ++j) {
            int nj = s_vlist[j];
            float sj = s_sc[nj];
            r += (sj > si) || (sj == si && nj < ni);
        }
        s_ord[r] = (unsigned short)ni;
    }
    __syncthreads();

    // --- greedy NMS (sequential over sorted positions, parallel suppress) ---
    for (int p = tid; p < V; p += NBLK) s_keep[p] = 1;
    __syncthreads();
    for (int i = 0; i < V; ++i) {
        if (s_keep[i]) {            // uniform branch: all threads read same value
            int ni = s_ord[i];
            float ax1 = s_x1[ni], ay1 = s_y1[ni], ax2 = s_x2[ni], ay2 = s_y2[ni];
            float areaA = (ax2 - ax1) * (ay2 - ay1);
            for (int j = i + 1 + tid; j < V; j += NBLK) {
                if (!s_keep[j]) continue;
                int nj = s_ord[j];
                float bx1 = s_x1[nj], by1 = s_y1[nj], bx2 = s_x2[nj], by2 = s_y2[nj];
                float areaB = (bx2 - bx1) * (by2 - by1);
                float lx = fmaxf(ax1, bx1), ly = fmaxf(ay1, by1);
                float rx = fminf(ax2, bx2), ry = fminf(ay2, by2);
                float iw = fmaxf(rx - lx, 0.0f), ih = fmaxf(ry - ly, 0.0f);
                float inter = iw * ih;
                float iou = inter / (areaA + areaB - inter + 1e-9f);
                if (iou > NMS_THRESH) s_keep[j] = 0;
            }
        }
        __syncthreads();
    }

    // --- compaction: kept (sorted order), suppressed (sorted order), invalid (index order) ---
    if (tid == 0) {
        int nk = 0, ns = 0;
        for (int p = 0; p < V; ++p) {
            if (s_keep[p]) { if (nk < NDET) s_keepOut[nk] = s_ord[p]; nk++; }
            else           { if (ns < NDET) s_supOut[ns] = s_ord[p]; ns++; }
        }
        s_K = nk;
        int ninv = 0;
        for (int n = 0; n < NPROP && ninv < NDET; ++n)
            if (s_sc[n] < 0.0f) s_invOut[ninv++] = (unsigned short)n;
    }
    __syncthreads();

    const int K = s_K;
    const int nsupT = V - K;   // total suppressed

    // output layout (flat float32): boxes[8000*4] | scores[8000] | labels[8000] | valid[8000]
    float* out_boxes  = out;
    float* out_scores = out + NFG * NDET * 4;
    float* out_labels = out + NFG * NDET * 4 + NFG * NDET;
    float* out_valid  = out + NFG * NDET * 4 + 2 * NFG * NDET;
    const int base = (c - 1) * NDET;

    for (int k = tid; k < NDET; k += NBLK) {
        int src; float sc, vf;
        if (k < K) {
            src = s_keepOut[k];
            sc = s_sc[src];
            vf = 1.0f;
        } else {
            int j = k - K;                       // K < NDET here
            src = (j < nsupT) ? s_supOut[j] : s_invOut[j - nsupT];
            sc = -1.0f;
            vf = 0.0f;
        }
        out_boxes[(base + k) * 4 + 0] = s_x1[src];
        out_boxes[(base + k) * 4 + 1] = s_y1[src];
        out_boxes[(base + k) * 4 + 2] = s_x2[src];
        out_boxes[(base + k) * 4 + 3] = s_y2[src];
        out_scores[base + k] = sc;
        out_labels[base + k] = (float)c;
        out_valid[base + k]  = vf;
    }
}

extern "C" void kernel_launch(void* const* d_in, const int* in_sizes, int n_in,
                              void* d_out, int out_size, void* d_ws, size_t ws_size,
                              hipStream_t stream) {
    const float* logits = (const float*)d_in[0];  // [2000, 81]
    const float* reg    = (const float*)d_in[1];  // [2000, 324]
    const float* prop   = (const float*)d_in[2];  // [2000, 4]
    float* out   = (float*)d_out;
    float* probs = (float*)d_ws;                  // 2000*81 floats = 648 KB

    softmax_kernel<<<(NPROP + 255) / 256, 256, 0, stream>>>(logits, probs);
    perclass_kernel<<<NFG, NBLK, 0, stream>>>(probs, reg, prop, out);
}

// Round 2
// 129.337 us; speedup vs baseline: 1.2340x; 1.2340x over previous
//
#include <hip/hip_runtime.h>
#include <math.h>

#define NPROP 2000
#define NCLS  81
#define NFG   80
#define NDET  100
#define NBLK  256

#define IMGW 800.0f
#define IMGH 800.0f
#define SCORE_THRESH 0.05f
#define NMS_THRESH 0.5f
#define MIN_SIZE 1.0f
#define BBOX_CLIP 4.135166556742356f  // log(1000/16)

// ---------------- kernel 1: per-row softmax stats (max, sum) ----------------
// Same sequential op order as the original full softmax -> scores bitwise equal.
__global__ void stats_kernel(const float* __restrict__ logits,
                             float* __restrict__ stats) {
    int n = blockIdx.x * 64 + threadIdx.x;
    if (n >= NPROP) return;
    const float* row = logits + n * NCLS;
    float m = -1e30f;
    for (int c = 0; c < NCLS; ++c) m = fmaxf(m, row[c]);
    float s = 0.0f;
    for (int c = 0; c < NCLS; ++c) s += expf(row[c] - m);
    stats[2 * n]     = m;
    stats[2 * n + 1] = s;
}

// ---------------- kernel 2: one block per foreground class ----------------
__global__ __launch_bounds__(NBLK) void perclass_kernel(
        const float* __restrict__ logits,  // [NPROP, NCLS]
        const float* __restrict__ stats,   // [NPROP, 2]
        const float* __restrict__ reg,     // [NPROP, NCLS*4]
        const float* __restrict__ prop,    // [NPROP, 4]
        float* __restrict__ out) {
    const int c   = blockIdx.x + 1;   // foreground class 1..80
    const int tid = threadIdx.x;
    const int lane = tid & 63;
    const int wv   = tid >> 6;

    // unsorted (by original proposal index)
    __shared__ float s_x1u[NPROP], s_y1u[NPROP], s_x2u[NPROP], s_y2u[NPROP];
    __shared__ float s_scu[NPROP];
    // sorted (by rank)
    __shared__ float s_x1s[NPROP], s_y1s[NPROP], s_x2s[NPROP], s_y2s[NPROP];
    __shared__ float s_scs[NPROP];
    __shared__ float s_vsc[NPROP];
    __shared__ unsigned short s_vlist[NPROP], s_ord[NPROP];
    __shared__ unsigned char  s_keep[NPROP];
    __shared__ unsigned short s_keepOut[NDET], s_supOut[NDET], s_invOut[NDET];
    __shared__ int s_cnt, s_wcnt[4];

    if (tid == 0) s_cnt = 0;
    __syncthreads();

    // --- decode + clip + validity ---
    for (int n = tid; n < NPROP; n += NBLK) {
        float lg = logits[n * NCLS + c];
        float m  = stats[2 * n];
        float sm = stats[2 * n + 1];
        float sc = expf(lg - m) / sm;

        float4 pr = ((const float4*)prop)[n];
        float w  = pr.z - pr.x, h = pr.w - pr.y;
        float cx = pr.x + 0.5f * w, cy = pr.y + 0.5f * h;
        float4 d = *(const float4*)(reg + (size_t)n * (NCLS * 4) + c * 4);
        float dx = d.x / 10.0f;
        float dy = d.y / 10.0f;
        float dw = fminf(d.z / 5.0f, BBOX_CLIP);
        float dh = fminf(d.w / 5.0f, BBOX_CLIP);
        float pcx = dx * w + cx;
        float pcy = dy * h + cy;
        float pw  = expf(dw) * w;
        float ph  = expf(dh) * h;
        float bx1 = fminf(fmaxf(pcx - 0.5f * pw, 0.0f), IMGW);
        float by1 = fminf(fmaxf(pcy - 0.5f * ph, 0.0f), IMGH);
        float bx2 = fminf(fmaxf(pcx + 0.5f * pw, 0.0f), IMGW);
        float by2 = fminf(fmaxf(pcy + 0.5f * ph, 0.0f), IMGH);
        s_x1u[n] = bx1; s_y1u[n] = by1; s_x2u[n] = bx2; s_y2u[n] = by2;
        bool valid = (sc >= SCORE_THRESH) && ((bx2 - bx1) >= MIN_SIZE)
                                          && ((by2 - by1) >= MIN_SIZE);
        s_scu[n] = valid ? sc : -1.0f;
        if (valid) {
            int p = atomicAdd(&s_cnt, 1);
            s_vlist[p] = (unsigned short)n;
            s_vsc[p]   = sc;
        }
    }
    __syncthreads();
    const int V = s_cnt;

    // --- rank sort of valid items: (score desc, index asc) ---
    for (int i = tid; i < V; i += NBLK) {
        float si = s_vsc[i];
        int   ni = s_vlist[i];
        int r = 0;
        for (int j = 0; j < V; ++j) {
            float sj = s_vsc[j];            // broadcast read
            int   nj = s_vlist[j];
            r += (sj > si) || (sj == si && nj < ni);
        }
        s_ord[r] = (unsigned short)ni;
        s_scs[r] = si;
    }
    __syncthreads();

    // --- gather sorted coords + init keep ---
    for (int p = tid; p < V; p += NBLK) {
        int n = s_ord[p];
        s_x1s[p] = s_x1u[n]; s_y1s[p] = s_y1u[n];
        s_x2s[p] = s_x2u[n]; s_y2s[p] = s_y2u[n];
        s_keep[p] = 1;
    }
    __syncthreads();

    // --- greedy NMS, barrier only on kept items, early stop at NDET kept ---
    int nkept = 0;
    for (int i = 0; i < V; ++i) {
        if (s_keep[i]) {                     // uniform (LDS broadcast)
            if (tid == 0) s_keepOut[nkept] = (unsigned short)i;
            nkept++;
            if (nkept == NDET) break;        // later suppressions can't affect output
            float ax1 = s_x1s[i], ay1 = s_y1s[i], ax2 = s_x2s[i], ay2 = s_y2s[i];
            float areaA = (ax2 - ax1) * (ay2 - ay1);
            for (int j = i + 1 + tid; j < V; j += NBLK) {
                if (!s_keep[j]) continue;
                float bx1 = s_x1s[j], by1 = s_y1s[j], bx2 = s_x2s[j], by2 = s_y2s[j];
                float areaB = (bx2 - bx1) * (by2 - by1);
                float lx = fmaxf(ax1, bx1), ly = fmaxf(ay1, by1);
                float rx = fminf(ax2, bx2), ry = fminf(ay2, by2);
                float iw = fmaxf(rx - lx, 0.0f), ih = fmaxf(ry - ly, 0.0f);
                float inter = iw * ih;
                float iou = inter / (areaA + areaB - inter + 1e-9f);
                if (iou > NMS_THRESH) s_keep[j] = 0;
            }
            __syncthreads();
        }
    }
    const int K = nkept;
    int nsup = 0;

    __syncthreads();   // s_keepOut visible; keep flags settled

    if (K < NDET) {
        nsup = V - K;   // NMS ran to completion
        // suppressed positions, ascending sorted position (first NDET)
        int base = 0;
        for (int start = 0; start < V && base < NDET; start += NBLK) {
            int p = start + tid;
            bool f = (p < V) && (!s_keep[p]);
            unsigned long long mb = __ballot(f);
            if (lane == 0) s_wcnt[wv] = __popcll(mb);
            __syncthreads();
            int wbase = base;
            for (int ww = 0; ww < wv; ++ww) wbase += s_wcnt[ww];
            if (f) {
                int pos = wbase + __popcll(mb & ((1ull << lane) - 1ull));
                if (pos < NDET) s_supOut[pos] = (unsigned short)p;
            }
            base += s_wcnt[0] + s_wcnt[1] + s_wcnt[2] + s_wcnt[3];
            __syncthreads();
        }
        // invalid proposals, ascending original index (first NDET)
        base = 0;
        for (int start = 0; start < NPROP && base < NDET; start += NBLK) {
            int n = start + tid;
            bool f = (n < NPROP) && (s_scu[n] < 0.0f);
            unsigned long long mb = __ballot(f);
            if (lane == 0) s_wcnt[wv] = __popcll(mb);
            __syncthreads();
            int wbase = base;
            for (int ww = 0; ww < wv; ++ww) wbase += s_wcnt[ww];
            if (f) {
                int pos = wbase + __popcll(mb & ((1ull << lane) - 1ull));
                if (pos < NDET) s_invOut[pos] = (unsigned short)n;
            }
            base += s_wcnt[0] + s_wcnt[1] + s_wcnt[2] + s_wcnt[3];
            __syncthreads();
        }
    }
    __syncthreads();

    // --- output: boxes | scores | labels | valid (class-major) ---
    float* out_boxes  = out;
    float* out_scores = out + NFG * NDET * 4;
    float* out_labels = out + NFG * NDET * 4 + NFG * NDET;
    float* out_valid  = out + NFG * NDET * 4 + 2 * NFG * NDET;
    const int base_o = (c - 1) * NDET;

    for (int k = tid; k < NDET; k += NBLK) {
        float bx1, by1, bx2, by2, sc, vf;
        if (k < K) {
            int p = s_keepOut[k];
            bx1 = s_x1s[p]; by1 = s_y1s[p]; bx2 = s_x2s[p]; by2 = s_y2s[p];
            sc = s_scs[p]; vf = 1.0f;
        } else {
            int j = k - K;
            if (j < nsup) {
                int p = s_supOut[j];
                bx1 = s_x1s[p]; by1 = s_y1s[p]; bx2 = s_x2s[p]; by2 = s_y2s[p];
            } else {
                int n = s_invOut[j - nsup];
                bx1 = s_x1u[n]; by1 = s_y1u[n]; bx2 = s_x2u[n]; by2 = s_y2u[n];
            }
            sc = -1.0f; vf = 0.0f;
        }
        out_boxes[(base_o + k) * 4 + 0] = bx1;
        out_boxes[(base_o + k) * 4 + 1] = by1;
        out_boxes[(base_o + k) * 4 + 2] = bx2;
        out_boxes[(base_o + k) * 4 + 3] = by2;
        out_scores[base_o + k] = sc;
        out_labels[base_o + k] = (float)c;
        out_valid[base_o + k]  = vf;
    }
}

extern "C" void kernel_launch(void* const* d_in, const int* in_sizes, int n_in,
                              void* d_out, int out_size, void* d_ws, size_t ws_size,
                              hipStream_t stream) {
    const float* logits = (const float*)d_in[0];  // [2000, 81]
    const float* reg    = (const float*)d_in[1];  // [2000, 324]
    const float* prop   = (const float*)d_in[2];  // [2000, 4]
    float* out   = (float*)d_out;
    float* stats = (float*)d_ws;                  // [2000, 2] floats

    stats_kernel<<<(NPROP + 63) / 64, 64, 0, stream>>>(logits, stats);
    perclass_kernel<<<NFG, NBLK, 0, stream>>>(logits, stats, reg, prop, out);
}